// Round 7
// baseline (726.148 us; speedup 1.0000x reference)
//
#include <hip/hip_runtime.h>
#include <hip/hip_bf16.h>

#define HID 512
#define BATCH 2048
#define NBLK 384
#define NTHR 256
#define GSTRIDE (NBLK * NTHR)

typedef __bf16 bf16x8 __attribute__((ext_vector_type(8)));
typedef float f32x4 __attribute__((ext_vector_type(4)));
typedef float f32x16 __attribute__((ext_vector_type(16)));
typedef __hip_bfloat16 bf16;

__device__ inline unsigned short f2bf(float x) {
    bf16 h = __float2bfloat16(x);
    return __builtin_bit_cast(unsigned short, h);
}
__device__ inline float bf2f(unsigned short u) {
    return __bfloat162float(__builtin_bit_cast(bf16, u));
}

__device__ inline void gload16(const void* g, void* l) {
    __builtin_amdgcn_global_load_lds((const __attribute__((address_space(1))) void*)g,
                                     (__attribute__((address_space(3))) void*)l, 16, 0, 0);
}

struct MegaArgs {
    const float *V, *t, *ipw, *ipb, *opw, *opb;
    const float *s0W, *s0b, *s2W, *s2b;
    const float *m1Wq, *m1Wk, *m1Wv, *m1bq, *m1bk, *m1bv, *m1igw, *m1igb, *m1lng, *m1lnb;
    const float *m3Wq, *m3Wk, *m3Wv, *m3bq, *m3bk, *m3bv, *m3igw, *m3igb, *m3lng, *m3lnb;
    bf16 *whi, *wlo, *hAhi, *hAlo, *hBhi, *hBlo;
    float *gq0, *gq1, *out;
    unsigned int *bar;
};

// software grid barrier (all NBLK blocks co-resident by capacity: 64KB LDS -> 2 blocks/CU)
__device__ inline void gridbar(unsigned int* bar) {
    __threadfence();
    __syncthreads();
    if (threadIdx.x == 0) {
        unsigned int g = atomicAdd(&bar[1], 0u);
        if (atomicAdd(&bar[0], 1u) == NBLK - 1) {
            atomicExch(&bar[0], 0u);
            __threadfence();
            atomicAdd(&bar[1], 1u);
        } else {
            while (atomicAdd(&bar[1], 0u) == g) __builtin_amdgcn_s_sleep(2);
        }
        __threadfence();
    }
    __syncthreads();
}

__global__ __launch_bounds__(NTHR, 2) void k_mega(MegaArgs a) {
    __shared__ __align__(16) bf16 smem[32768];   // 64 KB
    const int tid = threadIdx.x;
    const int bid = blockIdx.x;
    const int gtid = bid * NTHR + tid;
    const int w = tid >> 6, lane = tid & 63;

    // ================= phase 0: weight hi/lo split + input projection =================
    {
        const float* src[8] = { a.s0W, a.s2W, a.m1Wq, a.m1Wk, a.m1Wv, a.m3Wq, a.m3Wk, a.m3Wv };
        unsigned short* hi = (unsigned short*)a.whi;
        unsigned short* lo = (unsigned short*)a.wlo;
        for (int i4 = gtid; i4 < 917504; i4 += GSTRIDE) {
            int idx4 = i4 << 2;
            int seg, off;
            if (idx4 < 2097152) { seg = idx4 >> 20; off = idx4 & 1048575; }
            else { int r = idx4 - 2097152; seg = 2 + (r >> 18); off = r & 262143; }
            f32x4 wv = *(const f32x4*)(src[seg] + off);
            ushort4 h, l;
            h.x = f2bf(wv[0]); h.y = f2bf(wv[1]); h.z = f2bf(wv[2]); h.w = f2bf(wv[3]);
            l.x = f2bf(wv[0] - bf2f(h.x)); l.y = f2bf(wv[1] - bf2f(h.y));
            l.z = f2bf(wv[2] - bf2f(h.z)); l.w = f2bf(wv[3] - bf2f(h.w));
            *(ushort4*)(hi + idx4) = h;
            *(ushort4*)(lo + idx4) = l;
        }
        unsigned short* hhi = (unsigned short*)a.hAhi;
        unsigned short* hlo = (unsigned short*)a.hAlo;
        for (int i = gtid; i < 262144; i += GSTRIDE) {
            int b = i >> 7, j4 = (i & 127) << 2;
            float vv = a.V[b], tt = a.t[b];
            f32x4 w0 = *(const f32x4*)(a.ipw + 2 * j4);
            f32x4 w1 = *(const f32x4*)(a.ipw + 2 * j4 + 4);
            f32x4 bb = *(const f32x4*)(a.ipb + j4);
            float x[4] = { w0[0] * vv + w0[1] * tt + bb[0], w0[2] * vv + w0[3] * tt + bb[1],
                           w1[0] * vv + w1[1] * tt + bb[2], w1[2] * vv + w1[3] * tt + bb[3] };
            ushort4 h, l;
            h.x = f2bf(x[0]); h.y = f2bf(x[1]); h.z = f2bf(x[2]); h.w = f2bf(x[3]);
            l.x = f2bf(x[0] - bf2f(h.x)); l.y = f2bf(x[1] - bf2f(h.y));
            l.z = f2bf(x[2] - bf2f(h.z)); l.w = f2bf(x[3] - bf2f(h.w));
            size_t o = (size_t)b * HID + j4;
            *(ushort4*)(hhi + o) = h;
            *(ushort4*)(hlo + o) = l;
        }
    }

    // ================= GEMM phase (native-K split-bf16, split-K=2) =================
    // XCD x (bid&7) owns m-slab {2x,2x+1}: A-panels stay in one XCD's L2.
    auto GEMM = [&](const bf16* Ahi, const bf16* Alo,
                    const bf16* Wh0, const bf16* Wh1, const bf16* Wh2,
                    const bf16* Wl0, const bf16* Wl1, const bf16* Wl2) {
        const int xcd = bid & 7, slot = bid >> 3;       // slot 0..47
        const int kh = slot >= 24;
        const int s = slot - 24 * kh;                   // 0..23
        const int m0 = (xcd * 2 + s / 12) * 128;
        const int n0 = (s % 12) * 128;
        const int nseg = n0 >> 9, nloc = n0 & 511;
        const bf16* Wh = nseg == 0 ? Wh0 : (nseg == 1 ? Wh1 : Wh2);
        const bf16* Wl = nseg == 0 ? Wl0 : (nseg == 1 ? Wl1 : Wl2);
        const int kbase = kh * 256;

        const bf16* msrc = (w == 0) ? Ahi : (w == 1) ? Alo : (w == 2) ? Wh : Wl;
        const int rowbase = (w < 2) ? m0 : nloc;
        const size_t srow = (size_t)(rowbase + (lane & 31)) * HID + kbase + ((lane >> 5) << 3);
        bf16* const ldst = smem + (w << 12) + (lane << 3);

        auto STAGE = [&](int t, int bb) {
            const size_t kq = srow + (t << 5);
            bf16* db = ldst + bb * 16384;
#pragma unroll
            for (int p = 0; p < 8; ++p)
                gload16(msrc + kq + (size_t)((p >> 1) << 5) * HID + ((p & 1) << 4), db + (p << 9));
        };

        const int wm = w >> 1, wn = w & 1;
        f32x16 acc00 = {}, acc01 = {}, acc10 = {}, acc11 = {};

        STAGE(0, 0);
        __syncthreads();
        for (int t = 0; t < 8; ++t) {
            const int cur = t & 1;
            if (t < 7) STAGE(t + 1, cur ^ 1);
            const bf16* lb = smem + cur * 16384;
#pragma unroll
            for (int ks = 0; ks < 2; ++ks) {
                bf16x8 ah0 = *(const bf16x8*)(lb + ((((2*wm  ) << 1) + ks) << 9) + (lane << 3));
                bf16x8 ah1 = *(const bf16x8*)(lb + ((((2*wm+1) << 1) + ks) << 9) + (lane << 3));
                bf16x8 al0 = *(const bf16x8*)(lb + ((8 + ((2*wm  ) << 1) + ks) << 9) + (lane << 3));
                bf16x8 al1 = *(const bf16x8*)(lb + ((8 + ((2*wm+1) << 1) + ks) << 9) + (lane << 3));
                bf16x8 wh0 = *(const bf16x8*)(lb + ((16 + ((2*wn  ) << 1) + ks) << 9) + (lane << 3));
                bf16x8 wh1 = *(const bf16x8*)(lb + ((16 + ((2*wn+1) << 1) + ks) << 9) + (lane << 3));
                bf16x8 wl0 = *(const bf16x8*)(lb + ((24 + ((2*wn  ) << 1) + ks) << 9) + (lane << 3));
                bf16x8 wl1 = *(const bf16x8*)(lb + ((24 + ((2*wn+1) << 1) + ks) << 9) + (lane << 3));
                acc00 = __builtin_amdgcn_mfma_f32_32x32x16_bf16(ah0, wh0, acc00, 0, 0, 0);
                acc01 = __builtin_amdgcn_mfma_f32_32x32x16_bf16(ah0, wh1, acc01, 0, 0, 0);
                acc10 = __builtin_amdgcn_mfma_f32_32x32x16_bf16(ah1, wh0, acc10, 0, 0, 0);
                acc11 = __builtin_amdgcn_mfma_f32_32x32x16_bf16(ah1, wh1, acc11, 0, 0, 0);
                acc00 = __builtin_amdgcn_mfma_f32_32x32x16_bf16(al0, wh0, acc00, 0, 0, 0);
                acc01 = __builtin_amdgcn_mfma_f32_32x32x16_bf16(al0, wh1, acc01, 0, 0, 0);
                acc10 = __builtin_amdgcn_mfma_f32_32x32x16_bf16(al1, wh0, acc10, 0, 0, 0);
                acc11 = __builtin_amdgcn_mfma_f32_32x32x16_bf16(al1, wh1, acc11, 0, 0, 0);
                acc00 = __builtin_amdgcn_mfma_f32_32x32x16_bf16(ah0, wl0, acc00, 0, 0, 0);
                acc01 = __builtin_amdgcn_mfma_f32_32x32x16_bf16(ah0, wl1, acc01, 0, 0, 0);
                acc10 = __builtin_amdgcn_mfma_f32_32x32x16_bf16(ah1, wl0, acc10, 0, 0, 0);
                acc11 = __builtin_amdgcn_mfma_f32_32x32x16_bf16(ah1, wl1, acc11, 0, 0, 0);
            }
            __syncthreads();
        }

        float* Cp = kh ? a.gq1 : a.gq0;
        const f32x16* accs[2][2] = { { &acc00, &acc01 }, { &acc10, &acc11 } };
#pragma unroll
        for (int fi = 0; fi < 2; ++fi)
#pragma unroll
            for (int fj = 0; fj < 2; ++fj) {
                const f32x16& ac = *accs[fi][fj];
                const int col = n0 + ((2 * wn + fj) << 5) + (lane & 31);
                const int rbase = m0 + ((2 * wm + fi) << 5) + ((lane >> 5) << 2);
#pragma unroll
                for (int rr = 0; rr < 16; ++rr) {
                    int row = rbase + (rr & 3) + ((rr >> 2) << 3);
                    Cp[(size_t)row * 1536 + col] = ac[rr];
                }
            }
    };

    // ================= sLSTM activation phase =================
    auto SLSTM = [&](const float* bp, unsigned short* hhi, unsigned short* hlo) {
        for (int i = gtid; i < 262144; i += GSTRIDE) {
            int b = i >> 7, j4 = (i & 127) << 2;
            const float* r0 = a.gq0 + (size_t)b * 1536 + j4;
            const float* r1 = a.gq1 + (size_t)b * 1536 + j4;
            f32x4 gi = *(const f32x4*)r0 + *(const f32x4*)r1 + *(const f32x4*)(bp + j4);
            f32x4 gg = *(const f32x4*)(r0 + 512) + *(const f32x4*)(r1 + 512) + *(const f32x4*)(bp + 1024 + j4);
            f32x4 go = *(const f32x4*)(r0 + 1024) + *(const f32x4*)(r1 + 1024) + *(const f32x4*)(bp + 1536 + j4);
            ushort4 h, l;
            float x[4];
#pragma unroll
            for (int u = 0; u < 4; ++u)
                x[u] = tanhf(expf(gi[u]) * tanhf(gg[u])) / (1.f + expf(-go[u]));
            h.x = f2bf(x[0]); h.y = f2bf(x[1]); h.z = f2bf(x[2]); h.w = f2bf(x[3]);
            l.x = f2bf(x[0] - bf2f(h.x)); l.y = f2bf(x[1] - bf2f(h.y));
            l.z = f2bf(x[2] - bf2f(h.z)); l.w = f2bf(x[3] - bf2f(h.w));
            size_t o = (size_t)b * HID + j4;
            *(ushort4*)(hhi + o) = h;
            *(ushort4*)(hlo + o) = l;
        }
    };

    // ================= mLSTM phase (wave owns heads w and w+4; 6 rows/block) =================
    auto MLSTM = [&](const float* bq, const float* bk, const float* bv,
                     const bf16* hinh, const bf16* hinl,
                     const float* igw, const float* igb,
                     const float* lng, const float* lnb,
                     unsigned short* outh, unsigned short* outl, float* outp) {
        float* redf = (float*)smem;
        const int c0 = tid, c1 = tid + 256;
        const int h0 = w, h1 = w + 4;
        for (int it = 0; it < 6; ++it) {
            int row = bid + NBLK * it;
            if (row >= BATCH) break;
            const bf16* hh = hinh + (size_t)row * HID;
            const bf16* hl = hinl + (size_t)row * HID;
            const float* w0 = igw + h0 * HID;
            const float* w1 = igw + h1 * HID;
            float s0 = 0.f, s1 = 0.f;
#pragma unroll
            for (int k = 0; k < 8; ++k) {
                int p = lane + 64 * k;
                float hvp = __bfloat162float(hh[p]) + __bfloat162float(hl[p]);
                s0 += w0[p] * hvp; s1 += w1[p] * hvp;
            }
#pragma unroll
            for (int off = 32; off; off >>= 1) { s0 += __shfl_xor(s0, off); s1 += __shfl_xor(s1, off); }
            float ig0 = expf(s0 + igb[h0]);
            float ig1 = expf(s1 + igb[h1]);

            const float* r0 = a.gq0 + (size_t)row * 1536;
            const float* r1 = a.gq1 + (size_t)row * 1536;
            float q0 = r0[c0] + r1[c0] + bq[c0];
            float k0 = r0[512 + c0] + r1[512 + c0] + bk[c0];
            float v0 = r0[1024 + c0] + r1[1024 + c0] + bv[c0];
            float q1 = r0[c1] + r1[c1] + bq[c1];
            float k1 = r0[512 + c1] + r1[512 + c1] + bk[c1];
            float v1 = r0[1024 + c1] + r1[1024 + c1] + bv[c1];
            float kq0 = k0 * q0, vq0 = v0 * q0, kq1 = k1 * q1, vq1 = v1 * q1;
#pragma unroll
            for (int off = 32; off; off >>= 1) {
                kq0 += __shfl_xor(kq0, off); vq0 += __shfl_xor(vq0, off);
                kq1 += __shfl_xor(kq1, off); vq1 += __shfl_xor(vq1, off);
            }
            float hv0 = v0 * (ig0 * kq0) / (ig0 * (vq0 + 1.f) + 1e-6f);
            float hv1 = v1 * (ig1 * kq1) / (ig1 * (vq1 + 1.f) + 1e-6f);

            float t1 = hv0 + hv1, t2 = hv0 * hv0 + hv1 * hv1;
#pragma unroll
            for (int off = 32; off; off >>= 1) { t1 += __shfl_xor(t1, off); t2 += __shfl_xor(t2, off); }
            if (lane == 0) { redf[w] = t1; redf[4 + w] = t2; }
            __syncthreads();
            float u1 = redf[0] + redf[1] + redf[2] + redf[3];
            float u2 = redf[4] + redf[5] + redf[6] + redf[7];
            float mu = u1 * (1.f / 512.f);
            float var = u2 * (1.f / 512.f) - mu * mu;
            float rs = rsqrtf(var + 1e-5f);
            float o0 = (hv0 - mu) * rs * lng[c0] + lnb[c0];
            float o1 = (hv1 - mu) * rs * lng[c1] + lnb[c1];
            if (outp) {
                float po = o0 * a.opw[c0] + o1 * a.opw[c1];
#pragma unroll
                for (int off = 32; off; off >>= 1) po += __shfl_xor(po, off);
                if (lane == 0) redf[8 + w] = po;
                __syncthreads();
                if (tid == 0) outp[row] = redf[8] + redf[9] + redf[10] + redf[11] + a.opb[0];
            } else {
                unsigned short oh0 = f2bf(o0), oh1 = f2bf(o1);
                size_t p = (size_t)row * HID;
                outh[p + c0] = oh0;
                outl[p + c0] = f2bf(o0 - bf2f(oh0));
                outh[p + c1] = oh1;
                outl[p + c1] = f2bf(o1 - bf2f(oh1));
            }
            __syncthreads();
        }
    };

    // ================= the network =================
    gridbar(a.bar);
    // layer 0: sLSTM (W rows: i=0-511 g=1024-1535 o=1536-2047)
    GEMM(a.hAhi, a.hAlo,
         a.whi + 0, a.whi + 524288, a.whi + 786432,
         a.wlo + 0, a.wlo + 524288, a.wlo + 786432);
    gridbar(a.bar);
    SLSTM(a.s0b, (unsigned short*)a.hBhi, (unsigned short*)a.hBlo);
    gridbar(a.bar);
    // layer 1: mLSTM
    GEMM(a.hBhi, a.hBlo,
         a.whi + 2097152, a.whi + 2359296, a.whi + 2621440,
         a.wlo + 2097152, a.wlo + 2359296, a.wlo + 2621440);
    gridbar(a.bar);
    MLSTM(a.m1bq, a.m1bk, a.m1bv, a.hBhi, a.hBlo, a.m1igw, a.m1igb, a.m1lng, a.m1lnb,
          (unsigned short*)a.hAhi, (unsigned short*)a.hAlo, nullptr);
    gridbar(a.bar);
    // layer 2: sLSTM
    GEMM(a.hAhi, a.hAlo,
         a.whi + 1048576, a.whi + 1572864, a.whi + 1835008,
         a.wlo + 1048576, a.wlo + 1572864, a.wlo + 1835008);
    gridbar(a.bar);
    SLSTM(a.s2b, (unsigned short*)a.hBhi, (unsigned short*)a.hBlo);
    gridbar(a.bar);
    // layer 3: mLSTM + fused output projection
    GEMM(a.hBhi, a.hBlo,
         a.whi + 2883584, a.whi + 3145728, a.whi + 3407872,
         a.wlo + 2883584, a.wlo + 3145728, a.wlo + 3407872);
    gridbar(a.bar);
    MLSTM(a.m3bq, a.m3bk, a.m3bv, a.hBhi, a.hBlo, a.m3igw, a.m3igb, a.m3lng, a.m3lnb,
          nullptr, nullptr, a.out);
}

extern "C" void kernel_launch(void* const* d_in, const int* in_sizes, int n_in,
                              void* d_out, int out_size, void* d_ws, size_t ws_size,
                              hipStream_t stream) {
    char* ws = (char*)d_ws;
    MegaArgs a;
    a.V    = (const float*)d_in[0];
    a.t    = (const float*)d_in[1];
    a.ipw  = (const float*)d_in[2];
    a.ipb  = (const float*)d_in[3];
    a.opw  = (const float*)d_in[4];
    a.opb  = (const float*)d_in[5];
    a.s0W  = (const float*)d_in[6];
    a.s0b  = (const float*)d_in[7];
    a.s2W  = (const float*)d_in[9];
    a.s2b  = (const float*)d_in[10];
    a.m1Wq = (const float*)d_in[12];
    a.m1Wk = (const float*)d_in[13];
    a.m1Wv = (const float*)d_in[14];
    a.m1bq = (const float*)d_in[15];
    a.m1bk = (const float*)d_in[16];
    a.m1bv = (const float*)d_in[17];
    a.m1igw = (const float*)d_in[18];
    a.m1igb = (const float*)d_in[19];
    a.m1lng = (const float*)d_in[22];
    a.m1lnb = (const float*)d_in[23];
    a.m3Wq = (const float*)d_in[24];
    a.m3Wk = (const float*)d_in[25];
    a.m3Wv = (const float*)d_in[26];
    a.m3bq = (const float*)d_in[27];
    a.m3bk = (const float*)d_in[28];
    a.m3bv = (const float*)d_in[29];
    a.m3igw = (const float*)d_in[30];
    a.m3igb = (const float*)d_in[31];
    a.m3lng = (const float*)d_in[34];
    a.m3lnb = (const float*)d_in[35];

    a.whi  = (bf16*)ws;
    a.wlo  = (bf16*)(ws + 7340032);
    a.hAhi = (bf16*)(ws + 14680064);
    a.hAlo = (bf16*)(ws + 16777216);
    a.hBhi = (bf16*)(ws + 18874368);
    a.hBlo = (bf16*)(ws + 20971520);
    a.gq0  = (float*)(ws + 23068672);
    a.gq1  = (float*)(ws + 35651584);
    a.bar  = (unsigned int*)(ws + 48234496);
    a.out  = (float*)d_out;

    hipMemsetAsync(a.bar, 0, 8, stream);
    k_mega<<<NBLK, NTHR, 0, stream>>>(a);
}

// Round 9
// 127.512 us; speedup vs baseline: 5.6947x; 5.6947x over previous
//
#include <hip/hip_runtime.h>
#include <hip/hip_bf16.h>

#define HID 512
#define BATCH 2048

typedef __bf16 bf16x8 __attribute__((ext_vector_type(8)));
typedef float f32x4 __attribute__((ext_vector_type(4)));
typedef float f32x16 __attribute__((ext_vector_type(16)));
typedef __hip_bfloat16 bf16;

__device__ inline unsigned short f2bf(float x) {
    bf16 h = __float2bfloat16(x);
    return __builtin_bit_cast(unsigned short, h);
}
__device__ inline float bf2f(unsigned short u) {
    return __bfloat162float(__builtin_bit_cast(bf16, u));
}

__device__ inline void gload16(const void* g, void* l) {
    __builtin_amdgcn_global_load_lds((const __attribute__((address_space(1))) void*)g,
                                     (__attribute__((address_space(3))) void*)l, 16, 0, 0);
}

// ---------------- merged: weight fp32 -> hi/lo bf16 split  +  input projection ----------------
struct CvtArgs { const float* src[8]; };

__global__ void k_prep(CvtArgs a, unsigned short* __restrict__ hi, unsigned short* __restrict__ lo,
                       const float* __restrict__ V, const float* __restrict__ t,
                       const float* __restrict__ ipw, const float* __restrict__ ipb,
                       unsigned short* __restrict__ hhi, unsigned short* __restrict__ hlo) {
    const int bid = blockIdx.x;
    if (bid < 3584) {   // cvt part: 3,670,016 elems / 4
        int idx4 = (bid * 256 + threadIdx.x) << 2;
        int seg, off;
        if (idx4 < 2097152) { seg = idx4 >> 20; off = idx4 & 1048575; }
        else { int r = idx4 - 2097152; seg = 2 + (r >> 18); off = r & 262143; }
        f32x4 w = *(const f32x4*)(a.src[seg] + off);
        ushort4 h, l;
        h.x = f2bf(w[0]); h.y = f2bf(w[1]); h.z = f2bf(w[2]); h.w = f2bf(w[3]);
        l.x = f2bf(w[0] - bf2f(h.x)); l.y = f2bf(w[1] - bf2f(h.y));
        l.z = f2bf(w[2] - bf2f(h.z)); l.w = f2bf(w[3] - bf2f(h.w));
        *(ushort4*)(hi + idx4) = h;
        *(ushort4*)(lo + idx4) = l;
    } else {            // h0 part: B*HID/4 elems
        int idx = (bid - 3584) * 256 + threadIdx.x;
        int b = idx >> 7, j4 = (idx & 127) << 2;
        float vv = V[b], tt = t[b];
        f32x4 w0 = *(const f32x4*)(ipw + 2 * j4);
        f32x4 w1 = *(const f32x4*)(ipw + 2 * j4 + 4);
        f32x4 bb = *(const f32x4*)(ipb + j4);
        float x[4] = { w0[0] * vv + w0[1] * tt + bb[0], w0[2] * vv + w0[3] * tt + bb[1],
                       w1[0] * vv + w1[1] * tt + bb[2], w1[2] * vv + w1[3] * tt + bb[3] };
        ushort4 h, l;
        h.x = f2bf(x[0]); h.y = f2bf(x[1]); h.z = f2bf(x[2]); h.w = f2bf(x[3]);
        l.x = f2bf(x[0] - bf2f(h.x)); l.y = f2bf(x[1] - bf2f(h.y));
        l.z = f2bf(x[2] - bf2f(h.z)); l.w = f2bf(x[3] - bf2f(h.w));
        size_t o = (size_t)b * HID + j4;
        *(ushort4*)(hhi + o) = h;
        *(ushort4*)(hlo + o) = l;
    }
}

// ---------------- native-K split-bf16 GEMM, split-K=2, 3-deep counted-vmcnt pipeline ----------------
// C_kh[2048][1536] = Ah*Wh + Al*Wh + Ah*Wl over native K-half (256), no bias.
// Block 128x128, 4 waves, wave tile 64x64 = 2x2 frags of mfma_f32_32x32x16_bf16, BK=16.
// LDS: 3 buffers x 16KB; buffer = 16 chunks of 1KB; chunk c: matrix m=c>>2 (0=Ah,1=Al,2=Wh,3=Wl),
// rowblock rb=c&3. Chunk: lane l <-> row (l&31), k = 8*(l>>5) .. +8.
//
// Sync protocol (per iteration t): wait own STAGE(t) complete (vmcnt: 4 newer loads of
// STAGE(t+1) may stay in flight; TAIL: t=15 has only STAGE(15) outstanding -> vmcnt(0)),
// drain own LDS reads (lgkmcnt(0)) so the next writer of this buffer can't WAR-race,
// then s_barrier INSIDE asm-with-memory-clobber (real compiler fence: s_barrier builtin
// alone does not stop ds_read hoisting).
__global__ __launch_bounds__(256, 2) void k_gemm(
    const bf16* __restrict__ Ahi, const bf16* __restrict__ Alo,
    const bf16* __restrict__ Wh0, const bf16* __restrict__ Wh1, const bf16* __restrict__ Wh2,
    const bf16* __restrict__ Wl0, const bf16* __restrict__ Wl1, const bf16* __restrict__ Wl2,
    float* __restrict__ C0, float* __restrict__ C1)
{
    __shared__ __align__(16) bf16 lds[3][8192];   // 48 KB
    const int tid = threadIdx.x, w = tid >> 6, lane = tid & 63;

    // XCD x owns m-slabs {2x, 2x+1}: A-panels stay in one XCD's L2.
    const int bid = blockIdx.x;
    const int xcd = bid & 7, slot = bid >> 3;      // slot 0..47
    const int kh = slot >= 24;
    const int s = slot - 24 * kh;                  // 0..23
    const int m0 = (xcd * 2 + s / 12) * 128;
    const int n0 = (s % 12) * 128;
    const int nseg = n0 >> 9, nloc = n0 & 511;
    const bf16* Wh = nseg == 0 ? Wh0 : (nseg == 1 ? Wh1 : Wh2);
    const bf16* Wl = nseg == 0 ? Wl0 : (nseg == 1 ? Wl1 : Wl2);
    const int kbase = kh * 256;

    // wave w stages matrix w: 4 chunks (rowblocks 0..3) of the current 16-wide k-step
    const bf16* msrc = (w == 0) ? Ahi : (w == 1) ? Alo : (w == 2) ? Wh : Wl;
    const int rowbase = (w < 2) ? m0 : nloc;
    const size_t srow = (size_t)(rowbase + (lane & 31)) * HID + kbase + ((lane >> 5) << 3);

    auto STAGE = [&](int t) {
        bf16* db = &lds[t % 3][0] + (w << 11) + (lane << 3);
        const bf16* gp = msrc + srow + (t << 4);
#pragma unroll
        for (int p = 0; p < 4; ++p)
            gload16(gp + (size_t)(p << 5) * HID, db + (p << 9));
    };

    const int wm = w >> 1, wn = w & 1;
    const int la = lane << 3;
    f32x16 acc00 = {}, acc01 = {}, acc10 = {}, acc11 = {};

    STAGE(0);
    STAGE(1);
    for (int t = 0; t < 16; ++t) {
        if (t < 15)
            asm volatile("s_waitcnt vmcnt(4) lgkmcnt(0)\n\ts_barrier" ::: "memory");
        else
            asm volatile("s_waitcnt vmcnt(0) lgkmcnt(0)\n\ts_barrier" ::: "memory");
        if (t < 14) STAGE(t + 2);   // writes buf (t+2)%3 = (t-1)%3: reads drained above
        const bf16* lb = &lds[t % 3][0];
        bf16x8 ah0 = *(const bf16x8*)(lb + ((2 * wm    ) << 9) + la);
        bf16x8 ah1 = *(const bf16x8*)(lb + ((2 * wm + 1) << 9) + la);
        bf16x8 al0 = *(const bf16x8*)(lb + ((4 + 2 * wm    ) << 9) + la);
        bf16x8 al1 = *(const bf16x8*)(lb + ((4 + 2 * wm + 1) << 9) + la);
        bf16x8 wh0 = *(const bf16x8*)(lb + ((8 + 2 * wn    ) << 9) + la);
        bf16x8 wh1 = *(const bf16x8*)(lb + ((8 + 2 * wn + 1) << 9) + la);
        bf16x8 wl0 = *(const bf16x8*)(lb + ((12 + 2 * wn    ) << 9) + la);
        bf16x8 wl1 = *(const bf16x8*)(lb + ((12 + 2 * wn + 1) << 9) + la);
        acc00 = __builtin_amdgcn_mfma_f32_32x32x16_bf16(ah0, wh0, acc00, 0, 0, 0);
        acc01 = __builtin_amdgcn_mfma_f32_32x32x16_bf16(ah0, wh1, acc01, 0, 0, 0);
        acc10 = __builtin_amdgcn_mfma_f32_32x32x16_bf16(ah1, wh0, acc10, 0, 0, 0);
        acc11 = __builtin_amdgcn_mfma_f32_32x32x16_bf16(ah1, wh1, acc11, 0, 0, 0);
        acc00 = __builtin_amdgcn_mfma_f32_32x32x16_bf16(al0, wh0, acc00, 0, 0, 0);
        acc01 = __builtin_amdgcn_mfma_f32_32x32x16_bf16(al0, wh1, acc01, 0, 0, 0);
        acc10 = __builtin_amdgcn_mfma_f32_32x32x16_bf16(al1, wh0, acc10, 0, 0, 0);
        acc11 = __builtin_amdgcn_mfma_f32_32x32x16_bf16(al1, wh1, acc11, 0, 0, 0);
        acc00 = __builtin_amdgcn_mfma_f32_32x32x16_bf16(ah0, wl0, acc00, 0, 0, 0);
        acc01 = __builtin_amdgcn_mfma_f32_32x32x16_bf16(ah0, wl1, acc01, 0, 0, 0);
        acc10 = __builtin_amdgcn_mfma_f32_32x32x16_bf16(ah1, wl0, acc10, 0, 0, 0);
        acc11 = __builtin_amdgcn_mfma_f32_32x32x16_bf16(ah1, wl1, acc11, 0, 0, 0);
    }

    // epilogue: D layout col = lane&31, row = (rr&3) + 8*(rr>>2) + 4*(lane>>5)
    float* Cp = kh ? C1 : C0;
    const f32x16* accs[2][2] = { { &acc00, &acc01 }, { &acc10, &acc11 } };
#pragma unroll
    for (int fi = 0; fi < 2; ++fi)
#pragma unroll
        for (int fj = 0; fj < 2; ++fj) {
            const f32x16& ac = *accs[fi][fj];
            const int col = n0 + ((2 * wn + fj) << 5) + (lane & 31);
            const int rbase = m0 + ((2 * wm + fi) << 5) + ((lane >> 5) << 2);
#pragma unroll
            for (int rr = 0; rr < 16; ++rr) {
                int row = rbase + (rr & 3) + ((rr >> 2) << 3);
                Cp[(size_t)row * 1536 + col] = ac[rr];
            }
        }
}

// ---------------- sLSTM activation: sum partials + bias, h = sigm(o)*tanh(exp(i)*tanh(g)) ----------------
__global__ void k_slstm_act(const float* __restrict__ g0, const float* __restrict__ g1,
                            const float* __restrict__ bp,
                            unsigned short* __restrict__ hhi, unsigned short* __restrict__ hlo) {
    int idx = blockIdx.x * blockDim.x + threadIdx.x;   // B*HID/4
    int b = idx >> 7, j4 = (idx & 127) << 2;
    const float* r0 = g0 + (size_t)b * 1536 + j4;
    const float* r1 = g1 + (size_t)b * 1536 + j4;
    f32x4 gi = *(const f32x4*)r0 + *(const f32x4*)r1 + *(const f32x4*)(bp + j4);
    f32x4 gg = *(const f32x4*)(r0 + 512) + *(const f32x4*)(r1 + 512) + *(const f32x4*)(bp + 1024 + j4);
    f32x4 go = *(const f32x4*)(r0 + 1024) + *(const f32x4*)(r1 + 1024) + *(const f32x4*)(bp + 1536 + j4);
    ushort4 h, l;
    float x[4];
#pragma unroll
    for (int u = 0; u < 4; ++u)
        x[u] = tanhf(expf(gi[u]) * tanhf(gg[u])) / (1.f + expf(-go[u]));
    h.x = f2bf(x[0]); h.y = f2bf(x[1]); h.z = f2bf(x[2]); h.w = f2bf(x[3]);
    l.x = f2bf(x[0] - bf2f(h.x)); l.y = f2bf(x[1] - bf2f(h.y));
    l.z = f2bf(x[2] - bf2f(h.z)); l.w = f2bf(x[3] - bf2f(h.w));
    size_t o = (size_t)b * HID + j4;
    *(ushort4*)(hhi + o) = h;
    *(ushort4*)(hlo + o) = l;
}

// ---------------- mLSTM head math + layernorm (+optional fused final projection) ----------------
__global__ __launch_bounds__(512) void k_mlstm(
    const float* __restrict__ g0, const float* __restrict__ g1,
    const float* __restrict__ bq, const float* __restrict__ bk, const float* __restrict__ bv,
    const bf16* __restrict__ hinh, const bf16* __restrict__ hinl,
    const float* __restrict__ igw, const float* __restrict__ igb,
    const float* __restrict__ lng, const float* __restrict__ lnb,
    unsigned short* __restrict__ outh, unsigned short* __restrict__ outl,
    const float* __restrict__ opw, const float* __restrict__ opb, float* __restrict__ out)
{
    int b = blockIdx.x;
    int tid = threadIdx.x, head = tid >> 6, lane = tid & 63;

    const bf16*  hh = hinh + (size_t)b * HID;
    const bf16*  hl = hinl + (size_t)b * HID;
    const float* wrow = igw + head * HID;
    float s = 0.f;
#pragma unroll
    for (int k = 0; k < 8; ++k) {
        int p = lane + 64 * k;
        s += wrow[p] * (__bfloat162float(hh[p]) + __bfloat162float(hl[p]));
    }
#pragma unroll
    for (int off = 32; off; off >>= 1) s += __shfl_xor(s, off);
    float ig = expf(s + igb[head]);

    const float* r0 = g0 + (size_t)b * 1536;
    const float* r1 = g1 + (size_t)b * 1536;
    float q  = r0[tid] + r1[tid] + bq[tid];
    float kk = r0[512 + tid] + r1[512 + tid] + bk[tid];
    float v  = r0[1024 + tid] + r1[1024 + tid] + bv[tid];
    float kq = kk * q, vq = v * q;
#pragma unroll
    for (int off = 32; off; off >>= 1) { kq += __shfl_xor(kq, off); vq += __shfl_xor(vq, off); }
    float den = ig * (vq + 1.0f) + 1e-6f;
    float hv  = v * (ig * kq) / den;

    __shared__ float red[16];
    __shared__ float red2[8];
    float s1 = hv, s2 = hv * hv;
#pragma unroll
    for (int off = 32; off; off >>= 1) { s1 += __shfl_xor(s1, off); s2 += __shfl_xor(s2, off); }
    if (lane == 0) { red[head] = s1; red[8 + head] = s2; }
    __syncthreads();
    float t1 = 0.f, t2 = 0.f;
#pragma unroll
    for (int h2 = 0; h2 < 8; ++h2) { t1 += red[h2]; t2 += red[8 + h2]; }
    float mu  = t1 * (1.f / 512.f);
    float var = t2 * (1.f / 512.f) - mu * mu;
    float o = (hv - mu) * rsqrtf(var + 1e-5f) * lng[tid] + lnb[tid];

    if (out) {   // fused final projection (layer 3)
        float po = o * opw[tid];
#pragma unroll
        for (int off = 32; off; off >>= 1) po += __shfl_xor(po, off);
        if (lane == 0) red2[head] = po;
        __syncthreads();
        if (tid == 0) {
            float tt = 0.f;
#pragma unroll
            for (int h2 = 0; h2 < 8; ++h2) tt += red2[h2];
            out[b] = tt + opb[0];
        }
    } else {
        unsigned short oh = f2bf(o);
        size_t p = (size_t)b * HID + tid;
        outh[p] = oh;
        outl[p] = f2bf(o - bf2f(oh));
    }
}

extern "C" void kernel_launch(void* const* d_in, const int* in_sizes, int n_in,
                              void* d_out, int out_size, void* d_ws, size_t ws_size,
                              hipStream_t stream) {
    const float* V    = (const float*)d_in[0];
    const float* t    = (const float*)d_in[1];
    const float* ip_w = (const float*)d_in[2];
    const float* ip_b = (const float*)d_in[3];
    const float* op_w = (const float*)d_in[4];
    const float* op_b = (const float*)d_in[5];
    const float* s0_W = (const float*)d_in[6];
    const float* s0_b = (const float*)d_in[7];
    const float* s2_W = (const float*)d_in[9];
    const float* s2_b = (const float*)d_in[10];
    const float* m1_Wq = (const float*)d_in[12];
    const float* m1_Wk = (const float*)d_in[13];
    const float* m1_Wv = (const float*)d_in[14];
    const float* m1_bq = (const float*)d_in[15];
    const float* m1_bk = (const float*)d_in[16];
    const float* m1_bv = (const float*)d_in[17];
    const float* m1_igw = (const float*)d_in[18];
    const float* m1_igb = (const float*)d_in[19];
    const float* m1_lng = (const float*)d_in[22];
    const float* m1_lnb = (const float*)d_in[23];
    const float* m3_Wq = (const float*)d_in[24];
    const float* m3_Wk = (const float*)d_in[25];
    const float* m3_Wv = (const float*)d_in[26];
    const float* m3_bq = (const float*)d_in[27];
    const float* m3_bk = (const float*)d_in[28];
    const float* m3_bv = (const float*)d_in[29];
    const float* m3_igw = (const float*)d_in[30];
    const float* m3_igb = (const float*)d_in[31];
    const float* m3_lng = (const float*)d_in[34];
    const float* m3_lnb = (const float*)d_in[35];

    char* ws = (char*)d_ws;
    bf16* whi  = (bf16*)ws;                            // 3,670,016 elems
    bf16* wlo  = (bf16*)(ws + 7340032);
    bf16* hAhi = (bf16*)(ws + 14680064);               // [B][HID] each 2 MB
    bf16* hAlo = (bf16*)(ws + 16777216);
    bf16* hBhi = (bf16*)(ws + 18874368);
    bf16* hBlo = (bf16*)(ws + 20971520);
    float* gq0 = (float*)(ws + 23068672);              // [B][1536] f32 partial (khalf 0)
    float* gq1 = (float*)(ws + 23068672 + 12582912);   // [B][1536] f32 partial (khalf 1)

    CvtArgs ca;
    ca.src[0] = s0_W; ca.src[1] = s2_W;
    ca.src[2] = m1_Wq; ca.src[3] = m1_Wk; ca.src[4] = m1_Wv;
    ca.src[5] = m3_Wq; ca.src[6] = m3_Wk; ca.src[7] = m3_Wv;
    k_prep<<<4608, 256, 0, stream>>>(ca, (unsigned short*)whi, (unsigned short*)wlo,
                                     V, t, ip_w, ip_b,
                                     (unsigned short*)hAhi, (unsigned short*)hAlo);

    // layer 0: sLSTM (W rows: i=0-511, g=1024-1535, o=1536-2047)
    k_gemm<<<384, 256, 0, stream>>>(hAhi, hAlo,
        whi + 0, whi + 524288, whi + 786432,
        wlo + 0, wlo + 524288, wlo + 786432, gq0, gq1);
    k_slstm_act<<<1024, 256, 0, stream>>>(gq0, gq1, s0_b, (unsigned short*)hBhi, (unsigned short*)hBlo);
    // layer 1: mLSTM (fused q|k|v)
    k_gemm<<<384, 256, 0, stream>>>(hBhi, hBlo,
        whi + 2097152, whi + 2359296, whi + 2621440,
        wlo + 2097152, wlo + 2359296, wlo + 2621440, gq0, gq1);
    k_mlstm<<<BATCH, 512, 0, stream>>>(gq0, gq1, m1_bq, m1_bk, m1_bv, hBhi, hBlo,
                                       m1_igw, m1_igb, m1_lng, m1_lnb,
                                       (unsigned short*)hAhi, (unsigned short*)hAlo,
                                       nullptr, nullptr, nullptr);
    // layer 2: sLSTM
    k_gemm<<<384, 256, 0, stream>>>(hAhi, hAlo,
        whi + 1048576, whi + 1572864, whi + 1835008,
        wlo + 1048576, wlo + 1572864, wlo + 1835008, gq0, gq1);
    k_slstm_act<<<1024, 256, 0, stream>>>(gq0, gq1, s2_b, (unsigned short*)hBhi, (unsigned short*)hBlo);
    // layer 3: mLSTM + fused output projection
    k_gemm<<<384, 256, 0, stream>>>(hBhi, hBlo,
        whi + 2883584, whi + 3145728, whi + 3407872,
        wlo + 2883584, wlo + 3145728, wlo + 3407872, gq0, gq1);
    k_mlstm<<<BATCH, 512, 0, stream>>>(gq0, gq1, m3_bq, m3_bk, m3_bv, hBhi, hBlo,
                                       m3_igw, m3_igb, m3_lng, m3_lnb,
                                       nullptr, nullptr,
                                       op_w, op_b, (float*)d_out);
}